// Round 9
// baseline (199.991 us; speedup 1.0000x reference)
//
#include <hip/hip_runtime.h>
#include <math.h>

#define N_NODES 50000
#define N_EDGES 150000
#define LN_EPS 1e-5f

#define BM 256   // edge rows per tile
#define WM 64    // edge rows per wave (4 waves/block)

typedef _Float16 f16x8 __attribute__((ext_vector_type(8)));
typedef _Float16 f16x4 __attribute__((ext_vector_type(4)));
typedef _Float16 f16x2 __attribute__((ext_vector_type(2)));
typedef float    f32x4 __attribute__((ext_vector_type(4)));

// cvt_pkrtz returns __fp16-based vector; convert element-wise to _Float16 type
static __device__ __forceinline__ f16x2 pkrtz(float a, float b) {
    auto p = __builtin_amdgcn_cvt_pkrtz(a, b);
    f16x2 r; r[0] = (_Float16)p[0]; r[1] = (_Float16)p[1];
    return r;
}

// ---------------------------------------------------------------------------
// setup: blocks 0..65 build WtF (MFMA B-fragment order); blocks 66+ copy h->out
//   WtF frag index (c*4+nb)*64+l ; elem i: k=(l>>4)*8+i, e=nb*16+(l&15)
//   c < 64 : W[(e*64+c)*32+k]   (product chunks, f == c)
//   c >= 64: b[e*64+(c-64)*32+k] (bias chunks, A = h_j)
// ---------------------------------------------------------------------------
__global__ void setup_kernel(const float* __restrict__ W, const float* __restrict__ b,
                             const float* __restrict__ h,
                             f16x8* __restrict__ WtF, float* __restrict__ out) {
    int bid = blockIdx.x;
    if (bid < 66) {
        int tid = bid * 256 + threadIdx.x;
        int l  = tid & 63;
        int nb = (tid >> 6) & 3;
        int c  = tid >> 8;
        int k0 = (l >> 4) << 3;
        int e  = nb * 16 + (l & 15);
        const float* src = (c < 64) ? &W[(e * 64 + c) * 32 + k0]
                                    : &b[e * 64 + (c - 64) * 32 + k0];
        float4 v0 = *(const float4*)src;
        float4 v1 = *(const float4*)(src + 4);
        f16x8 o;
        o[0] = (_Float16)v0.x; o[1] = (_Float16)v0.y; o[2] = (_Float16)v0.z; o[3] = (_Float16)v0.w;
        o[4] = (_Float16)v1.x; o[5] = (_Float16)v1.y; o[6] = (_Float16)v1.z; o[7] = (_Float16)v1.w;
        WtF[tid] = o;
    } else {
        int tid = (bid - 66) * 256 + threadIdx.x;   // 3125 blocks cover 800000 float4
        ((float4*)out)[tid] = ((const float4*)h)[tid];
    }
}

// ---------------------------------------------------------------------------
// edge: fp16 MFMA GEMM, K-split x2. Block (tile, s) computes product chunks
// [32s, 32s+32) for 256 edges; split 1 also adds the bias chunks. Doubles
// resident waves at constant per-wave B-traffic (disjoint WtF halves).
// ---------------------------------------------------------------------------
__launch_bounds__(256, 3)
__global__ void edge_kernel(const float* __restrict__ ea,   // [N_EDGES][32]
                            const float* __restrict__ h,    // [N_NODES][64]
                            const int*   __restrict__ ei,   // [2][N_EDGES]
                            const f16x8* __restrict__ WtF,  // fragment-major
                            float* __restrict__ out)        // [N_NODES][64]
{
    __shared__ _Float16 s_hj[BM][68];  // stride 68 f16: col reads conflict-free
    __shared__ int      s_src[BM];

    const int t     = threadIdx.x;
    const int tile  = blockIdx.x >> 1;
    const int s     = blockIdx.x & 1;
    const int m_base = tile * BM;
    const int cbase  = s * 32;

    // ---- stage gathered h_j rows (f32 -> f16) + src indices, one row/thread ----
    {
        int gm = m_base + t;
        if (gm < N_EDGES) {
            s_src[t] = ei[gm];
            const float4* hr = (const float4*)&h[(size_t)ei[N_EDGES + gm] * 64];
            #pragma unroll
            for (int j = 0; j < 16; ++j) {
                float4 v = hr[j];
                f16x2 p0 = pkrtz(v.x, v.y);
                f16x2 p1 = pkrtz(v.z, v.w);
                f16x4 o; o[0] = p0[0]; o[1] = p0[1]; o[2] = p1[0]; o[3] = p1[1];
                *(f16x4*)&s_hj[t][j * 4] = o;
            }
        } else {
            s_src[t] = -1;
            f16x4 z = (f16x4){0, 0, 0, 0};
            #pragma unroll
            for (int j = 0; j < 16; ++j)
                *(f16x4*)&s_hj[t][j * 4] = z;
        }
    }

    const int lane = t & 63;
    const int w    = t >> 6;
    const int r16  = lane & 15;
    const int g    = lane >> 4;
    const int k0   = g * 8;
    const int row0 = w * WM;
    int rows[4];
    #pragma unroll
    for (int a = 0; a < 4; ++a) rows[a] = row0 + a * 16 + r16;

    // ---- ea A-slices as f16 pairs: fixed per lane for the whole K loop ----
    f16x2 eap[4][4];
    #pragma unroll
    for (int a = 0; a < 4; ++a) {
        int gm = m_base + rows[a];
        if (gm < N_EDGES) {
            float4 v0 = *(const float4*)&ea[(size_t)gm * 32 + k0];
            float4 v1 = *(const float4*)&ea[(size_t)gm * 32 + k0 + 4];
            eap[a][0] = pkrtz(v0.x, v0.y);
            eap[a][1] = pkrtz(v0.z, v0.w);
            eap[a][2] = pkrtz(v1.x, v1.y);
            eap[a][3] = pkrtz(v1.z, v1.w);
        } else {
            #pragma unroll
            for (int i = 0; i < 4; ++i) eap[a][i] = (f16x2){0, 0};
        }
    }

    f32x4 acc[4][4];
    #pragma unroll
    for (int a = 0; a < 4; ++a)
        #pragma unroll
        for (int nb = 0; nb < 4; ++nb)
            acc[a][nb] = (f32x4){0.f, 0.f, 0.f, 0.f};

    __syncthreads();   // only barrier in the kernel

    // ---- B prefetch buffers (3-deep, disjoint WtF half per split) ----
    f16x8 b0[4], b1[4], b2[4];
    #pragma unroll
    for (int nb = 0; nb < 4; ++nb) b0[nb] = WtF[((cbase + 0) * 4 + nb) * 64 + lane];
    #pragma unroll
    for (int nb = 0; nb < 4; ++nb) b1[nb] = WtF[((cbase + 1) * 4 + nb) * 64 + lane];
    #pragma unroll
    for (int nb = 0; nb < 4; ++nb) b2[nb] = WtF[((cbase + 2) * 4 + nb) * 64 + lane];

    _Float16 hc[4];
    #pragma unroll
    for (int a = 0; a < 4; ++a) hc[a] = s_hj[rows[a]][cbase];

    // product-chunk step: compute chunk c with B-regs bb, read hj col c+1
    auto step = [&](int c, f16x8* bb, bool loadnext) {
        _Float16 hn[4] = {0, 0, 0, 0};
        if (loadnext) {
            #pragma unroll
            for (int a = 0; a < 4; ++a) hn[a] = s_hj[rows[a]][c + 1];
        }
        #pragma unroll
        for (int a = 0; a < 4; ++a) {
            f16x2 hs; hs[0] = hc[a]; hs[1] = hc[a];
            f16x2 p0 = eap[a][0] * hs;
            f16x2 p1 = eap[a][1] * hs;
            f16x2 p2 = eap[a][2] * hs;
            f16x2 p3 = eap[a][3] * hs;
            f16x8 va;
            va[0] = p0[0]; va[1] = p0[1]; va[2] = p1[0]; va[3] = p1[1];
            va[4] = p2[0]; va[5] = p2[1]; va[6] = p3[0]; va[7] = p3[1];
            #pragma unroll
            for (int nb = 0; nb < 4; ++nb)
                acc[a][nb] = __builtin_amdgcn_mfma_f32_16x16x32_f16(va, bb[nb], acc[a][nb], 0, 0, 0);
        }
        #pragma unroll
        for (int a = 0; a < 4; ++a) hc[a] = hn[a];
    };

    // ---- main loop: 10 triples cover chunks cbase..cbase+29; prefetch runs ahead ----
    for (int c = cbase; c < cbase + 30; c += 3) {
        step(c, b0, true);
        #pragma unroll
        for (int nb = 0; nb < 4; ++nb) b0[nb] = WtF[((c + 3) * 4 + nb) * 64 + lane];
        step(c + 1, b1, true);
        #pragma unroll
        for (int nb = 0; nb < 4; ++nb) b1[nb] = WtF[((c + 4) * 4 + nb) * 64 + lane];
        step(c + 2, b2, true);
        #pragma unroll
        for (int nb = 0; nb < 4; ++nb) b2[nb] = WtF[((c + 5) * 4 + nb) * 64 + lane];
    }
    // after loop: b0 = cbase+30, b1 = cbase+31, b2 = cbase+32 (split1: chunk 64)
    step(cbase + 30, b0, true);
    if (s) {   // split 1: prefetch bias chunk 65 into b0
        #pragma unroll
        for (int nb = 0; nb < 4; ++nb) b0[nb] = WtF[(65 * 4 + nb) * 64 + lane];
    }
    step(cbase + 31, b1, false);

    // ---- bias chunks (split 1 only, added once): A = h_j straight from LDS ----
    if (s) {
        #pragma unroll
        for (int half = 0; half < 2; ++half) {
            f16x8* bb = half ? b0 : b2;   // chunk 64 = b2, chunk 65 = b0
            #pragma unroll
            for (int a = 0; a < 4; ++a) {
                f16x4 lo = *(const f16x4*)&s_hj[rows[a]][half * 32 + k0];
                f16x4 hi = *(const f16x4*)&s_hj[rows[a]][half * 32 + k0 + 4];
                f16x8 va;
                va[0] = lo[0]; va[1] = lo[1]; va[2] = lo[2]; va[3] = lo[3];
                va[4] = hi[0]; va[5] = hi[1]; va[6] = hi[2]; va[7] = hi[3];
                #pragma unroll
                for (int nb = 0; nb < 4; ++nb)
                    acc[a][nb] = __builtin_amdgcn_mfma_f32_16x16x32_f16(va, bb[nb], acc[a][nb], 0, 0, 0);
            }
        }
    }

    // ---- scatter-add partial sums (C/D: col = lane&15, row = (lane>>4)*4+reg) ----
    #pragma unroll
    for (int a = 0; a < 4; ++a) {
        #pragma unroll
        for (int r = 0; r < 4; ++r) {
            int srcn = s_src[row0 + a * 16 + g * 4 + r];
            if (srcn >= 0) {
                #pragma unroll
                for (int nb = 0; nb < 4; ++nb)
                    atomicAdd(&out[(size_t)srcn * 64 + nb * 16 + r16], acc[a][nb][r]);
            }
        }
    }
}

// ---------------------------------------------------------------------------
// ln: in-place LayerNorm, one wave per row
// ---------------------------------------------------------------------------
__global__ void ln_kernel(const float* __restrict__ gamma, const float* __restrict__ beta,
                          float* __restrict__ out) {
    int row = blockIdx.x * 4 + (threadIdx.x >> 6);
    int lane = threadIdx.x & 63;
    if (row >= N_NODES) return;
    float x = out[row * 64 + lane];
    float s = x;
    #pragma unroll
    for (int o = 32; o; o >>= 1) s += __shfl_xor(s, o);
    float mu = s * (1.0f / 64.0f);
    float d = x - mu;
    float v = d * d;
    #pragma unroll
    for (int o = 32; o; o >>= 1) v += __shfl_xor(v, o);
    float var = v * (1.0f / 64.0f);
    float r = rsqrtf(var + LN_EPS);
    out[row * 64 + lane] = d * r * gamma[lane] + beta[lane];
}

// ---------------------------------------------------------------------------
extern "C" void kernel_launch(void* const* d_in, const int* in_sizes, int n_in,
                              void* d_out, int out_size, void* d_ws, size_t ws_size,
                              hipStream_t stream) {
    const float* h     = (const float*)d_in[0];
    const float* ea    = (const float*)d_in[1];
    const float* W     = (const float*)d_in[2];
    const float* b     = (const float*)d_in[3];
    const float* gamma = (const float*)d_in[4];
    const float* beta  = (const float*)d_in[5];
    const int*   ei    = (const int*)d_in[6];
    float* out = (float*)d_out;

    f16x8* WtF = (f16x8*)d_ws;   // 66*4*64 f16x8 = 264 KB

    setup_kernel<<<66 + 3125, 256, 0, stream>>>(W, b, h, WtF, out);
    edge_kernel<<<2 * ((N_EDGES + BM - 1) / BM), 256, 0, stream>>>(ea, h, ei, WtF, out);
    ln_kernel<<<(N_NODES + 3) / 4, 256, 0, stream>>>(gamma, beta, out);
}

// Round 10
// 162.994 us; speedup vs baseline: 1.2270x; 1.2270x over previous
//
#include <hip/hip_runtime.h>
#include <math.h>

#define N_NODES 50000
#define N_EDGES 150000
#define LN_EPS 1e-5f

#define BM 256   // edge rows per block
#define WM 64    // edge rows per wave; 8 waves = 4 row-groups x 2 N-halves

typedef _Float16 f16x8 __attribute__((ext_vector_type(8)));
typedef _Float16 f16x4 __attribute__((ext_vector_type(4)));
typedef _Float16 f16x2 __attribute__((ext_vector_type(2)));
typedef float    f32x4 __attribute__((ext_vector_type(4)));

// cvt_pkrtz returns __fp16-based vector; convert element-wise to _Float16 type
static __device__ __forceinline__ f16x2 pkrtz(float a, float b) {
    auto p = __builtin_amdgcn_cvt_pkrtz(a, b);
    f16x2 r; r[0] = (_Float16)p[0]; r[1] = (_Float16)p[1];
    return r;
}

// ---------------------------------------------------------------------------
// setup: blocks 0..65 build WtF (MFMA B-fragment order); blocks 66+ copy h->out
//   WtF frag index (c*4+nb)*64+l ; elem i: k=(l>>4)*8+i, e=nb*16+(l&15)
//   c < 64 : W[(e*64+c)*32+k]    (product chunks, f == c)
//   c >= 64: b[e*64+(c-64)*32+k] (bias chunks, A = h_j)
// ---------------------------------------------------------------------------
__global__ void setup_kernel(const float* __restrict__ W, const float* __restrict__ b,
                             const float* __restrict__ h,
                             f16x8* __restrict__ WtF, float* __restrict__ out) {
    int bid = blockIdx.x;
    if (bid < 66) {
        int tid = bid * 256 + threadIdx.x;
        int l  = tid & 63;
        int nb = (tid >> 6) & 3;
        int c  = tid >> 8;
        int k0 = (l >> 4) << 3;
        int e  = nb * 16 + (l & 15);
        const float* src = (c < 64) ? &W[(e * 64 + c) * 32 + k0]
                                    : &b[e * 64 + (c - 64) * 32 + k0];
        float4 v0 = *(const float4*)src;
        float4 v1 = *(const float4*)(src + 4);
        f16x8 o;
        o[0] = (_Float16)v0.x; o[1] = (_Float16)v0.y; o[2] = (_Float16)v0.z; o[3] = (_Float16)v0.w;
        o[4] = (_Float16)v1.x; o[5] = (_Float16)v1.y; o[6] = (_Float16)v1.z; o[7] = (_Float16)v1.w;
        WtF[tid] = o;
    } else {
        int tid = (bid - 66) * 256 + threadIdx.x;   // 3125 blocks cover 800000 float4
        ((float4*)out)[tid] = ((const float4*)h)[tid];
    }
}

// ---------------------------------------------------------------------------
// edge: fp16 MFMA GEMM, N-split. 8 waves = (4 row-groups) x (2 N-halves);
// each wave: 64 rows x 32 cols, reads only its WtF half -> total B-traffic
// unchanged vs round 8 while wave count doubles. hj staged once per block.
// ---------------------------------------------------------------------------
__launch_bounds__(512, 4)
__global__ void edge_kernel(const float* __restrict__ ea,   // [N_EDGES][32]
                            const float* __restrict__ h,    // [N_NODES][64]
                            const int*   __restrict__ ei,   // [2][N_EDGES]
                            const f16x8* __restrict__ WtF,  // fragment-major
                            float* __restrict__ out)        // [N_NODES][64]
{
    __shared__ _Float16 s_hj[BM][68];  // stride 68 f16: col reads conflict-free
    __shared__ int      s_src[BM];

    const int t = threadIdx.x;
    const int m_base = blockIdx.x * BM;

    // ---- stage gathered h_j rows (f32 -> f16) + src indices, half-row/thread ----
    {
        int row  = t >> 1;
        int half = t & 1;
        int gm   = m_base + row;
        if (gm < N_EDGES) {
            if (half == 0) s_src[row] = ei[gm];
            const float4* hr = (const float4*)&h[(size_t)ei[N_EDGES + gm] * 64 + half * 32];
            #pragma unroll
            for (int j = 0; j < 8; ++j) {
                float4 v = hr[j];
                f16x2 p0 = pkrtz(v.x, v.y);
                f16x2 p1 = pkrtz(v.z, v.w);
                f16x4 o; o[0] = p0[0]; o[1] = p0[1]; o[2] = p1[0]; o[3] = p1[1];
                *(f16x4*)&s_hj[row][half * 32 + j * 4] = o;
            }
        } else {
            if (half == 0) s_src[row] = -1;
            f16x4 z = (f16x4){0, 0, 0, 0};
            #pragma unroll
            for (int j = 0; j < 8; ++j)
                *(f16x4*)&s_hj[row][half * 32 + j * 4] = z;
        }
    }

    const int lane = t & 63;
    const int wid  = t >> 6;       // 0..7
    const int wrow = wid & 3;      // row group
    const int wn   = wid >> 2;     // N half (0/1)
    const int nb0  = wn * 2;       // this wave's first nb (cols nb0*16..nb0*16+31)
    const int r16  = lane & 15;
    const int g    = lane >> 4;
    const int k0   = g * 8;
    const int row0 = wrow * WM;
    int rows[4];
    #pragma unroll
    for (int a = 0; a < 4; ++a) rows[a] = row0 + a * 16 + r16;

    // ---- ea A-slices as f16 pairs: fixed per lane for the whole K loop ----
    f16x2 eap[4][4];
    #pragma unroll
    for (int a = 0; a < 4; ++a) {
        int gm = m_base + rows[a];
        if (gm < N_EDGES) {
            float4 v0 = *(const float4*)&ea[(size_t)gm * 32 + k0];
            float4 v1 = *(const float4*)&ea[(size_t)gm * 32 + k0 + 4];
            eap[a][0] = pkrtz(v0.x, v0.y);
            eap[a][1] = pkrtz(v0.z, v0.w);
            eap[a][2] = pkrtz(v1.x, v1.y);
            eap[a][3] = pkrtz(v1.z, v1.w);
        } else {
            #pragma unroll
            for (int i = 0; i < 4; ++i) eap[a][i] = (f16x2){0, 0};
        }
    }

    f32x4 acc[4][2];
    #pragma unroll
    for (int a = 0; a < 4; ++a)
        #pragma unroll
        for (int nb = 0; nb < 2; ++nb)
            acc[a][nb] = (f32x4){0.f, 0.f, 0.f, 0.f};

    __syncthreads();   // only barrier in the kernel

    // ---- B prefetch buffers (3-deep, 2 frags each = this wave's N half) ----
    f16x8 b0[2], b1[2], b2[2];
    #pragma unroll
    for (int j = 0; j < 2; ++j) b0[j] = WtF[(0 * 4 + nb0 + j) * 64 + lane];
    #pragma unroll
    for (int j = 0; j < 2; ++j) b1[j] = WtF[(1 * 4 + nb0 + j) * 64 + lane];
    #pragma unroll
    for (int j = 0; j < 2; ++j) b2[j] = WtF[(2 * 4 + nb0 + j) * 64 + lane];

    _Float16 hc[4];
    #pragma unroll
    for (int a = 0; a < 4; ++a) hc[a] = s_hj[rows[a]][0];

    // product-chunk step: compute chunk c with B-regs bb, read hj col c+1
    auto step = [&](int c, f16x8* bb, bool loadnext) {
        _Float16 hn[4] = {0, 0, 0, 0};
        if (loadnext) {
            #pragma unroll
            for (int a = 0; a < 4; ++a) hn[a] = s_hj[rows[a]][c + 1];
        }
        #pragma unroll
        for (int a = 0; a < 4; ++a) {
            f16x2 hs; hs[0] = hc[a]; hs[1] = hc[a];
            f16x2 p0 = eap[a][0] * hs;
            f16x2 p1 = eap[a][1] * hs;
            f16x2 p2 = eap[a][2] * hs;
            f16x2 p3 = eap[a][3] * hs;
            f16x8 va;
            va[0] = p0[0]; va[1] = p0[1]; va[2] = p1[0]; va[3] = p1[1];
            va[4] = p2[0]; va[5] = p2[1]; va[6] = p3[0]; va[7] = p3[1];
            #pragma unroll
            for (int j = 0; j < 2; ++j)
                acc[a][j] = __builtin_amdgcn_mfma_f32_16x16x32_f16(va, bb[j], acc[a][j], 0, 0, 0);
        }
        #pragma unroll
        for (int a = 0; a < 4; ++a) hc[a] = hn[a];
    };

    // ---- main loop: 21 triples cover product chunks 0..62; prefetch to 65 ----
    for (int c = 0; c < 63; c += 3) {
        step(c, b0, true);
        #pragma unroll
        for (int j = 0; j < 2; ++j) b0[j] = WtF[((c + 3) * 4 + nb0 + j) * 64 + lane];
        step(c + 1, b1, true);
        #pragma unroll
        for (int j = 0; j < 2; ++j) b1[j] = WtF[((c + 4) * 4 + nb0 + j) * 64 + lane];
        step(c + 2, b2, true);
        #pragma unroll
        for (int j = 0; j < 2; ++j) b2[j] = WtF[((c + 5) * 4 + nb0 + j) * 64 + lane];
    }
    // after loop: b0 = chunk 63 (product), b1 = 64 (bias), b2 = 65 (bias)
    step(63, b0, false);

    // ---- bias chunks: A = h_j (f16, straight from LDS), each wave its own nb ----
    #pragma unroll
    for (int half = 0; half < 2; ++half) {
        f16x8* bb = half ? b2 : b1;
        #pragma unroll
        for (int a = 0; a < 4; ++a) {
            f16x4 lo = *(const f16x4*)&s_hj[rows[a]][half * 32 + k0];
            f16x4 hi = *(const f16x4*)&s_hj[rows[a]][half * 32 + k0 + 4];
            f16x8 va;
            va[0] = lo[0]; va[1] = lo[1]; va[2] = lo[2]; va[3] = lo[3];
            va[4] = hi[0]; va[5] = hi[1]; va[6] = hi[2]; va[7] = hi[3];
            #pragma unroll
            for (int j = 0; j < 2; ++j)
                acc[a][j] = __builtin_amdgcn_mfma_f32_16x16x32_f16(va, bb[j], acc[a][j], 0, 0, 0);
        }
    }

    // ---- scatter-add (C/D: col = lane&15, row = (lane>>4)*4 + reg) ----
    #pragma unroll
    for (int a = 0; a < 4; ++a) {
        #pragma unroll
        for (int r = 0; r < 4; ++r) {
            int srcn = s_src[row0 + a * 16 + g * 4 + r];
            if (srcn >= 0) {
                #pragma unroll
                for (int j = 0; j < 2; ++j)
                    atomicAdd(&out[(size_t)srcn * 64 + (nb0 + j) * 16 + r16], acc[a][j][r]);
            }
        }
    }
}

// ---------------------------------------------------------------------------
// ln: in-place LayerNorm, one wave per row
// ---------------------------------------------------------------------------
__global__ void ln_kernel(const float* __restrict__ gamma, const float* __restrict__ beta,
                          float* __restrict__ out) {
    int row = blockIdx.x * 4 + (threadIdx.x >> 6);
    int lane = threadIdx.x & 63;
    if (row >= N_NODES) return;
    float x = out[row * 64 + lane];
    float s = x;
    #pragma unroll
    for (int o = 32; o; o >>= 1) s += __shfl_xor(s, o);
    float mu = s * (1.0f / 64.0f);
    float d = x - mu;
    float v = d * d;
    #pragma unroll
    for (int o = 32; o; o >>= 1) v += __shfl_xor(v, o);
    float var = v * (1.0f / 64.0f);
    float r = rsqrtf(var + LN_EPS);
    out[row * 64 + lane] = d * r * gamma[lane] + beta[lane];
}

// ---------------------------------------------------------------------------
extern "C" void kernel_launch(void* const* d_in, const int* in_sizes, int n_in,
                              void* d_out, int out_size, void* d_ws, size_t ws_size,
                              hipStream_t stream) {
    const float* h     = (const float*)d_in[0];
    const float* ea    = (const float*)d_in[1];
    const float* W     = (const float*)d_in[2];
    const float* b     = (const float*)d_in[3];
    const float* gamma = (const float*)d_in[4];
    const float* beta  = (const float*)d_in[5];
    const int*   ei    = (const int*)d_in[6];
    float* out = (float*)d_out;

    f16x8* WtF = (f16x8*)d_ws;   // 66*4*64 f16x8 = 264 KB

    setup_kernel<<<66 + 3125, 256, 0, stream>>>(W, b, h, WtF, out);
    edge_kernel<<<(N_EDGES + BM - 1) / BM, 512, 0, stream>>>(ea, h, ei, WtF, out);
    ln_kernel<<<(N_NODES + 3) / 4, 256, 0, stream>>>(gamma, beta, out);
}

// Round 11
// 157.729 us; speedup vs baseline: 1.2679x; 1.0334x over previous
//
#include <hip/hip_runtime.h>
#include <math.h>

#define N_NODES 50000
#define N_EDGES 150000
#define LN_EPS 1e-5f

#define BM 256   // edge rows per block; 8 waves x (32 rows x 64 cols)

typedef _Float16 f16x8 __attribute__((ext_vector_type(8)));
typedef _Float16 f16x4 __attribute__((ext_vector_type(4)));
typedef _Float16 f16x2 __attribute__((ext_vector_type(2)));
typedef float    f32x4 __attribute__((ext_vector_type(4)));

// cvt_pkrtz returns __fp16-based vector; convert element-wise to _Float16 type
static __device__ __forceinline__ f16x2 pkrtz(float a, float b) {
    auto p = __builtin_amdgcn_cvt_pkrtz(a, b);
    f16x2 r; r[0] = (_Float16)p[0]; r[1] = (_Float16)p[1];
    return r;
}

// ---------------------------------------------------------------------------
// setup: blocks 0..65 build WtF (MFMA B-fragment order); blocks 66+ copy h->out
//   WtF frag index (c*4+nb)*64+l ; elem i: k=(l>>4)*8+i, e=nb*16+(l&15)
//   c < 64 : W[(e*64+c)*32+k]    (product chunks, f == c)
//   c >= 64: b[e*64+(c-64)*32+k] (bias chunks, A = h_j)
// ---------------------------------------------------------------------------
__global__ void setup_kernel(const float* __restrict__ W, const float* __restrict__ b,
                             const float* __restrict__ h,
                             f16x8* __restrict__ WtF, float* __restrict__ out) {
    int bid = blockIdx.x;
    if (bid < 66) {
        int tid = bid * 256 + threadIdx.x;
        int l  = tid & 63;
        int nb = (tid >> 6) & 3;
        int c  = tid >> 8;
        int k0 = (l >> 4) << 3;
        int e  = nb * 16 + (l & 15);
        const float* src = (c < 64) ? &W[(e * 64 + c) * 32 + k0]
                                    : &b[e * 64 + (c - 64) * 32 + k0];
        float4 v0 = *(const float4*)src;
        float4 v1 = *(const float4*)(src + 4);
        f16x8 o;
        o[0] = (_Float16)v0.x; o[1] = (_Float16)v0.y; o[2] = (_Float16)v0.z; o[3] = (_Float16)v0.w;
        o[4] = (_Float16)v1.x; o[5] = (_Float16)v1.y; o[6] = (_Float16)v1.z; o[7] = (_Float16)v1.w;
        WtF[tid] = o;
    } else {
        // 1563 blocks x 512 float4 cover 800000 float4 (h -> out)
        int base = (bid - 66) * 512 + threadIdx.x;
        if (base < 800000) ((float4*)out)[base] = ((const float4*)h)[base];
        int base2 = base + 256;
        if (base2 < 800000) ((float4*)out)[base2] = ((const float4*)h)[base2];
    }
}

// ---------------------------------------------------------------------------
// edge: fp16 MFMA GEMM, B staged in LDS (shared by 8 waves -> 4x less L2
// B-traffic). Double-buffered groups of 4 chunks, reg-staged (issue-early /
// ds_write-late), one barrier per group. Bias chunks in a side LDS buffer.
// ---------------------------------------------------------------------------
__launch_bounds__(512, 4)
__global__ void edge_kernel(const float* __restrict__ ea,   // [N_EDGES][32]
                            const float* __restrict__ h,    // [N_NODES][64]
                            const int*   __restrict__ ei,   // [2][N_EDGES]
                            const f16x8* __restrict__ WtF,  // fragment-major
                            float* __restrict__ out)        // [N_NODES][64]
{
    __shared__ _Float16 s_hj[BM][68];   // 34.8 KB; b64 col reads conflict-free
    __shared__ int      s_src[BM];      // 1 KB
    __shared__ f16x8    s_b[2][1024];   // 2 x 16 KB: double-buffered 4-chunk group
    __shared__ f16x8    s_bias[512];    // 8 KB: bias chunks 64,65

    const int t = threadIdx.x;
    const int m_base = blockIdx.x * BM;

    // ---- stage gathered h_j rows (f32 -> f16) + src indices, half-row/thread ----
    {
        int row  = t >> 1;
        int half = t & 1;
        int gm   = m_base + row;
        if (gm < N_EDGES) {
            if (half == 0) s_src[row] = ei[gm];
            const float4* hr = (const float4*)&h[(size_t)ei[N_EDGES + gm] * 64 + half * 32];
            #pragma unroll
            for (int j = 0; j < 8; ++j) {
                float4 v = hr[j];
                f16x2 p0 = pkrtz(v.x, v.y);
                f16x2 p1 = pkrtz(v.z, v.w);
                f16x4 o; o[0] = p0[0]; o[1] = p0[1]; o[2] = p1[0]; o[3] = p1[1];
                *(f16x4*)&s_hj[row][half * 32 + j * 4] = o;
            }
        } else {
            if (half == 0) s_src[row] = -1;
            f16x4 z = (f16x4){0, 0, 0, 0};
            #pragma unroll
            for (int j = 0; j < 8; ++j)
                *(f16x4*)&s_hj[row][half * 32 + j * 4] = z;
        }
    }

    const int lane = t & 63;
    const int wid  = t >> 6;       // 0..7
    const int r16  = lane & 15;
    const int g    = lane >> 4;
    const int k0   = g * 8;
    const int row0 = wid * 32;
    int rows[2];
    rows[0] = row0 + r16;
    rows[1] = row0 + 16 + r16;

    // ---- ea A-slices as f16 pairs: fixed per lane for the whole K loop ----
    f16x2 eap[2][4];
    #pragma unroll
    for (int a = 0; a < 2; ++a) {
        int gm = m_base + rows[a];
        if (gm < N_EDGES) {
            float4 v0 = *(const float4*)&ea[(size_t)gm * 32 + k0];
            float4 v1 = *(const float4*)&ea[(size_t)gm * 32 + k0 + 4];
            eap[a][0] = pkrtz(v0.x, v0.y);
            eap[a][1] = pkrtz(v0.z, v0.w);
            eap[a][2] = pkrtz(v1.x, v1.y);
            eap[a][3] = pkrtz(v1.z, v1.w);
        } else {
            #pragma unroll
            for (int i = 0; i < 4; ++i) eap[a][i] = (f16x2){0, 0};
        }
    }

    f32x4 acc[2][4];
    #pragma unroll
    for (int a = 0; a < 2; ++a)
        #pragma unroll
        for (int nb = 0; nb < 4; ++nb)
            acc[a][nb] = (f32x4){0.f, 0.f, 0.f, 0.f};

    // ---- prologue staging: bias (8KB) + group 0 (16KB), coalesced b128 ----
    {
        f16x8 rb = WtF[16384 + t];          // bias chunks 64,65
        f16x8 r0 = WtF[t];                  // group 0 first half
        f16x8 r1 = WtF[512 + t];            // group 0 second half
        s_bias[t]        = rb;
        s_b[0][t]        = r0;
        s_b[0][512 + t]  = r1;
    }

    __syncthreads();

    // ---- main loop: 16 groups x 4 chunks; dbuf, 1 barrier/group ----
    int buf = 0;
    for (int grp = 0; grp < 16; ++grp) {
        f16x8 ra, rb2;
        if (grp < 15) {                      // issue next-group loads early
            ra  = WtF[(grp + 1) * 1024 + t];
            rb2 = WtF[(grp + 1) * 1024 + 512 + t];
        }
        // hj for this group's 4 chunks (one b64 per a-group)
        f16x4 hv[2];
        hv[0] = *(const f16x4*)&s_hj[rows[0]][grp * 4];
        hv[1] = *(const f16x4*)&s_hj[rows[1]][grp * 4];

        #pragma unroll
        for (int cc = 0; cc < 4; ++cc) {
            f16x8 bf[4];
            #pragma unroll
            for (int nb = 0; nb < 4; ++nb)
                bf[nb] = s_b[buf][(cc * 4 + nb) * 64 + lane];
            #pragma unroll
            for (int a = 0; a < 2; ++a) {
                f16x2 hs; hs[0] = hv[a][cc]; hs[1] = hv[a][cc];
                f16x2 p0 = eap[a][0] * hs;
                f16x2 p1 = eap[a][1] * hs;
                f16x2 p2 = eap[a][2] * hs;
                f16x2 p3 = eap[a][3] * hs;
                f16x8 va;
                va[0] = p0[0]; va[1] = p0[1]; va[2] = p1[0]; va[3] = p1[1];
                va[4] = p2[0]; va[5] = p2[1]; va[6] = p3[0]; va[7] = p3[1];
                #pragma unroll
                for (int nb = 0; nb < 4; ++nb)
                    acc[a][nb] = __builtin_amdgcn_mfma_f32_16x16x32_f16(va, bf[nb], acc[a][nb], 0, 0, 0);
            }
        }
        if (grp < 15) {                      // write next group into other buffer
            s_b[buf ^ 1][t]       = ra;
            s_b[buf ^ 1][512 + t] = rb2;
        }
        __syncthreads();
        buf ^= 1;
    }

    // ---- bias chunks 64,65: A = h_j straight from LDS ----
    #pragma unroll
    for (int half = 0; half < 2; ++half) {
        #pragma unroll
        for (int a = 0; a < 2; ++a) {
            f16x4 lo = *(const f16x4*)&s_hj[rows[a]][half * 32 + k0];
            f16x4 hi = *(const f16x4*)&s_hj[rows[a]][half * 32 + k0 + 4];
            f16x8 va;
            va[0] = lo[0]; va[1] = lo[1]; va[2] = lo[2]; va[3] = lo[3];
            va[4] = hi[0]; va[5] = hi[1]; va[6] = hi[2]; va[7] = hi[3];
            #pragma unroll
            for (int nb = 0; nb < 4; ++nb) {
                f16x8 bf = s_bias[(half * 4 + nb) * 64 + lane];
                acc[a][nb] = __builtin_amdgcn_mfma_f32_16x16x32_f16(va, bf, acc[a][nb], 0, 0, 0);
            }
        }
    }

    // ---- scatter-add (C/D: col = lane&15, row = (lane>>4)*4 + reg) ----
    #pragma unroll
    for (int a = 0; a < 2; ++a) {
        #pragma unroll
        for (int r = 0; r < 4; ++r) {
            int srcn = s_src[row0 + a * 16 + g * 4 + r];
            if (srcn >= 0) {
                #pragma unroll
                for (int nb = 0; nb < 4; ++nb)
                    atomicAdd(&out[(size_t)srcn * 64 + nb * 16 + r16], acc[a][nb][r]);
            }
        }
    }
}

// ---------------------------------------------------------------------------
// ln: in-place LayerNorm, 16 threads per row (float4 each), coalesced
// ---------------------------------------------------------------------------
__global__ void ln_kernel(const float* __restrict__ gamma, const float* __restrict__ beta,
                          float* __restrict__ out) {
    int t = threadIdx.x;
    int row = blockIdx.x * 16 + (t >> 4);    // 3125 blocks x 16 rows = 50000 exact
    int s = t & 15;
    float4 v = *(float4*)&out[(size_t)row * 64 + s * 4];
    float sum = v.x + v.y + v.z + v.w;
    #pragma unroll
    for (int o = 1; o < 16; o <<= 1) sum += __shfl_xor(sum, o);
    float mu = sum * (1.0f / 64.0f);
    float dx = v.x - mu, dy = v.y - mu, dz = v.z - mu, dw = v.w - mu;
    float vs = dx * dx + dy * dy + dz * dz + dw * dw;
    #pragma unroll
    for (int o = 1; o < 16; o <<= 1) vs += __shfl_xor(vs, o);
    float r = rsqrtf(vs * (1.0f / 64.0f) + LN_EPS);
    float4 gv = *(const float4*)&gamma[s * 4];
    float4 bv = *(const float4*)&beta[s * 4];
    float4 o4;
    o4.x = dx * r * gv.x + bv.x;
    o4.y = dy * r * gv.y + bv.y;
    o4.z = dz * r * gv.z + bv.z;
    o4.w = dw * r * gv.w + bv.w;
    *(float4*)&out[(size_t)row * 64 + s * 4] = o4;
}

// ---------------------------------------------------------------------------
extern "C" void kernel_launch(void* const* d_in, const int* in_sizes, int n_in,
                              void* d_out, int out_size, void* d_ws, size_t ws_size,
                              hipStream_t stream) {
    const float* h     = (const float*)d_in[0];
    const float* ea    = (const float*)d_in[1];
    const float* W     = (const float*)d_in[2];
    const float* b     = (const float*)d_in[3];
    const float* gamma = (const float*)d_in[4];
    const float* beta  = (const float*)d_in[5];
    const int*   ei    = (const int*)d_in[6];
    float* out = (float*)d_out;

    f16x8* WtF = (f16x8*)d_ws;   // 66*4*64 f16x8 = 264 KB

    setup_kernel<<<66 + 1563, 256, 0, stream>>>(W, b, h, WtF, out);
    edge_kernel<<<(N_EDGES + BM - 1) / BM, 512, 0, stream>>>(ea, h, ei, WtF, out);
    ln_kernel<<<N_NODES / 16, 256, 0, stream>>>(gamma, beta, out);
}